// Round 2
// baseline (2284.827 us; speedup 1.0000x reference)
//
#include <hip/hip_runtime.h>
#include <hip/hip_bf16.h>

// ---------- bf16 helpers (for optional bf16 h fallback) ----------
__device__ __forceinline__ float bf2f(unsigned short u) {
    return __uint_as_float(((unsigned int)u) << 16);
}
__device__ __forceinline__ unsigned short f2bf(float f) {
    unsigned int u = __float_as_uint(f);
    return (unsigned short)((u + 0x7FFFu + ((u >> 16) & 1u)) >> 16);
}

// ---------- detect whether edge_index is int64 (odd words all zero) ----------
__global__ void detect_idx64_kernel(const int* __restrict__ e, int* __restrict__ flag) {
    if (threadIdx.x == 0 && blockIdx.x == 0) {
        int z = 0;
#pragma unroll
        for (int i = 0; i < 16; ++i) z |= e[2 * i + 1];
        *flag = (z == 0) ? 1 : 0;
    }
}

// ---------- scatter: agg[dst] += feat[src]; optional cnt[dst] += 1 ----------
template <bool SRC_BF16, bool COUNT>
__global__ void scatter_kernel(const void* __restrict__ feat,
                               const int* __restrict__ eidx, int n_edges,
                               float* __restrict__ agg, float* __restrict__ cnt,
                               const int* __restrict__ idx64_flag) {
    long long t = (long long)blockIdx.x * blockDim.x + threadIdx.x;
    long long total = (long long)n_edges * 16;
    if (t >= total) return;
    int e = (int)(t >> 4);
    int q = (int)(t & 15);                 // 16 quads of 4 features = 64
    const bool i64 = (*idx64_flag != 0);   // wave-uniform branch
    int s, d;
    if (i64) {                             // int64: value k at 32-bit word 2k (low)
        s = eidx[2 * e];
        d = eidx[2 * (n_edges + e)];
    } else {
        s = eidx[e];
        d = eidx[n_edges + e];
    }
    float v0, v1, v2, v3;
    if (SRC_BF16) {
        const ushort4 u = *reinterpret_cast<const ushort4*>(
            (const unsigned short*)feat + (size_t)s * 64 + q * 4);
        v0 = bf2f(u.x); v1 = bf2f(u.y); v2 = bf2f(u.z); v3 = bf2f(u.w);
    } else {
        const float4 v = *reinterpret_cast<const float4*>(
            (const float*)feat + (size_t)s * 64 + q * 4);
        v0 = v.x; v1 = v.y; v2 = v.z; v3 = v.w;
    }
    float* ad = agg + (size_t)d * 64 + q * 4;
    unsafeAtomicAdd(ad + 0, v0);
    unsafeAtomicAdd(ad + 1, v1);
    unsafeAtomicAdd(ad + 2, v2);
    unsafeAtomicAdd(ad + 3, v3);
    if (COUNT && q == 0) unsafeAtomicAdd(cnt + d, 1.0f);
}

// ---------- dense layer: out = [relu]( (agg/deg) Wl^T + xin Wr^T + b ) ----------
// 256 threads = 4 nodes x 64 lanes; 32 nodes per block (8 iterations) to
// amortize the LDS weight staging. Weights f32 [OUT_DIM, 64].
template <int OUT_DIM, bool RELU, bool IN_BF16, bool OUT_BF16>
__global__ void sage_layer_kernel(const void* __restrict__ xin,
                                  const float* __restrict__ agg,
                                  const float* __restrict__ cnt,
                                  const float* __restrict__ Wl,
                                  const float* __restrict__ Wr,
                                  const float* __restrict__ bias,
                                  void* __restrict__ out, int n_nodes) {
    __shared__ float sWl[OUT_DIM][65];   // stride 65: 32 lanes hit 32 distinct banks
    __shared__ float sWr[OUT_DIM][65];
    __shared__ float sB[OUT_DIM];
    __shared__ float sA[4][64];
    __shared__ float sX[4][64];

    for (int idx = threadIdx.x; idx < OUT_DIM * 64; idx += 256) {
        int r = idx >> 6, c = idx & 63;
        sWl[r][c] = Wl[idx];
        sWr[r][c] = Wr[idx];
    }
    if (threadIdx.x < OUT_DIM) sB[threadIdx.x] = bias[threadIdx.x];

    const int g = threadIdx.x >> 6;   // node slot (wave id)
    const int j = threadIdx.x & 63;   // lane
    const int base = blockIdx.x * 32;

#pragma unroll
    for (int it = 0; it < 8; ++it) {
        const int node = base + it * 4 + g;
        __syncthreads();              // weights ready / previous compute done
        if (node < n_nodes) {
            float inv = 1.0f / fmaxf(cnt[node], 1.0f);
            sA[g][j] = agg[(size_t)node * 64 + j] * inv;
            sX[g][j] = IN_BF16
                ? bf2f(((const unsigned short*)xin)[(size_t)node * 64 + j])
                : ((const float*)xin)[(size_t)node * 64 + j];
        }
        __syncthreads();
        if (node < n_nodes && j < OUT_DIM) {
            float acc = sB[j];
#pragma unroll
            for (int k = 0; k < 64; ++k) {
                acc = fmaf(sA[g][k], sWl[j][k], acc);   // sA: broadcast (same addr/wave)
                acc = fmaf(sX[g][k], sWr[j][k], acc);
            }
            if (RELU) acc = fmaxf(acc, 0.0f);
            if (OUT_BF16)
                ((unsigned short*)out)[(size_t)node * OUT_DIM + j] = f2bf(acc);
            else
                ((float*)out)[(size_t)node * OUT_DIM + j] = acc;
        }
    }
}

extern "C" void kernel_launch(void* const* d_in, const int* in_sizes, int n_in,
                              void* d_out, int out_size, void* d_ws, size_t ws_size,
                              hipStream_t stream) {
    const float* x   = (const float*)d_in[0];   // [N,64] f32
    const int*   ei  = (const int*)d_in[1];     // [2,E] int32 (or int64 -> detected)
    const float* W1l = (const float*)d_in[2];   // [64,64] f32
    const float* W1r = (const float*)d_in[3];
    const float* b1  = (const float*)d_in[4];
    const float* W2l = (const float*)d_in[5];   // [40,64] f32
    const float* W2r = (const float*)d_in[6];
    const float* b2  = (const float*)d_in[7];
    float* out = (float*)d_out;                 // [N,40] f32

    const int n_nodes = in_sizes[0] / 64;
    const int n_edges = in_sizes[1] / 2;

    const size_t aggN = (size_t)n_nodes * 64;             // f32 elements
    const size_t agg_bytes = aggN * sizeof(float);        // 25.6 MB
    const size_t h_f32_bytes = agg_bytes;
    const size_t h_bf16_bytes = aggN * sizeof(unsigned short);
    const size_t cnt_bytes = (size_t)n_nodes * sizeof(float);

    const bool h_is_f32 = ws_size >= agg_bytes + h_f32_bytes + cnt_bytes + 64;

    char* ws = (char*)d_ws;
    float* agg = (float*)ws;                       ws += agg_bytes;
    void*  h   = (void*)ws;                        ws += (h_is_f32 ? h_f32_bytes : h_bf16_bytes);
    float* cnt = (float*)ws;                       ws += cnt_bytes;
    int*   idx64_flag = (int*)ws;

    detect_idx64_kernel<<<1, 64, 0, stream>>>(ei, idx64_flag);

    hipMemsetAsync(agg, 0, agg_bytes, stream);
    hipMemsetAsync(cnt, 0, cnt_bytes, stream);

    const long long total = (long long)n_edges * 16;
    const int sblocks = (int)((total + 255) / 256);

    // layer-1 aggregation: agg += x[src], cnt += 1
    scatter_kernel<false, true><<<sblocks, 256, 0, stream>>>(
        x, ei, n_edges, agg, cnt, idx64_flag);

    // layer-1 dense: h = relu(agg/deg * W1l^T + x * W1r^T + b1)
    const int lblocks = (n_nodes + 31) / 32;
    if (h_is_f32)
        sage_layer_kernel<64, true, false, false><<<lblocks, 256, 0, stream>>>(
            x, agg, cnt, W1l, W1r, b1, h, n_nodes);
    else
        sage_layer_kernel<64, true, false, true><<<lblocks, 256, 0, stream>>>(
            x, agg, cnt, W1l, W1r, b1, h, n_nodes);

    hipMemsetAsync(agg, 0, agg_bytes, stream);

    // layer-2 aggregation: agg += h[src]
    if (h_is_f32)
        scatter_kernel<false, false><<<sblocks, 256, 0, stream>>>(
            h, ei, n_edges, agg, cnt, idx64_flag);
    else
        scatter_kernel<true, false><<<sblocks, 256, 0, stream>>>(
            h, ei, n_edges, agg, cnt, idx64_flag);

    // layer-2 dense: out = agg/deg * W2l^T + h * W2r^T + b2  (f32 out)
    if (h_is_f32)
        sage_layer_kernel<40, false, false, false><<<lblocks, 256, 0, stream>>>(
            h, agg, cnt, W2l, W2r, b2, out, n_nodes);
    else
        sage_layer_kernel<40, false, true, false><<<lblocks, 256, 0, stream>>>(
            h, agg, cnt, W2l, W2r, b2, out, n_nodes);
}

// Round 3
// 645.471 us; speedup vs baseline: 3.5398x; 3.5398x over previous
//
#include <hip/hip_runtime.h>
#include <hip/hip_bf16.h>

// ---------- bf16 helpers (only used for low-workspace fallback) ----------
__device__ __forceinline__ float bf2f(unsigned short u) {
    return __uint_as_float(((unsigned int)u) << 16);
}
__device__ __forceinline__ unsigned short f2bf(float f) {
    unsigned int u = __float_as_uint(f);
    return (unsigned short)((u + 0x7FFFu + ((u >> 16) & 1u)) >> 16);
}

// ---------- detect whether edge_index is int64 (odd 32-bit words all zero) ----------
__global__ void detect_idx64_kernel(const int* __restrict__ e, int* __restrict__ flag) {
    if (threadIdx.x == 0 && blockIdx.x == 0) {
        int z = 0;
#pragma unroll
        for (int i = 0; i < 16; ++i) z |= e[2 * i + 1];
        *flag = (z == 0) ? 1 : 0;
    }
}

// ---------- CSR build: histogram of dst ----------
__global__ void hist_kernel(const int* __restrict__ eidx, int n_edges,
                            int* __restrict__ deg, const int* __restrict__ flag) {
    int e = blockIdx.x * blockDim.x + threadIdx.x;
    if (e >= n_edges) return;
    const bool i64 = (*flag != 0);
    int d = i64 ? eidx[2 * (n_edges + e)] : eidx[n_edges + e];
    atomicAdd(&deg[d], 1);
}

// ---------- CSR build: single-block exclusive scan (N=100k, L2-resident) ----------
#define SCAN_THREADS 1024
__global__ void scan_kernel(const int* __restrict__ deg, int* __restrict__ off, int n) {
    __shared__ int sums[SCAN_THREADS];
    const int t = threadIdx.x;
    const int chunk = (n + SCAN_THREADS - 1) / SCAN_THREADS;
    const int lo = t * chunk;
    const int hi = (lo + chunk < n) ? lo + chunk : n;
    int s = 0;
    for (int i = lo; i < hi; ++i) s += deg[i];
    sums[t] = s;
    __syncthreads();
    // Hillis-Steele inclusive scan
    for (int d = 1; d < SCAN_THREADS; d <<= 1) {
        int v = (t >= d) ? sums[t - d] : 0;
        __syncthreads();
        sums[t] += v;
        __syncthreads();
    }
    int run = (t == 0) ? 0 : sums[t - 1];
    for (int i = lo; i < hi; ++i) { off[i] = run; run += deg[i]; }
    if (t == SCAN_THREADS - 1 && hi == n) off[n] = run;
}

// ---------- CSR build: fill edge lists (cursor = copy of off) ----------
__global__ void fill_kernel(const int* __restrict__ eidx, int n_edges,
                            int* __restrict__ cursor, int* __restrict__ csr,
                            const int* __restrict__ flag) {
    int e = blockIdx.x * blockDim.x + threadIdx.x;
    if (e >= n_edges) return;
    const bool i64 = (*flag != 0);
    int s, d;
    if (i64) { s = eidx[2 * e]; d = eidx[2 * (n_edges + e)]; }
    else     { s = eidx[e];     d = eidx[n_edges + e]; }
    int pos = atomicAdd(&cursor[d], 1);
    csr[pos] = s;
}

// ---------- fused layer: out = [relu]( mean_gather(feat) Wl^T + feat Wr^T + b ) ----------
// 256 threads = 4 waves; wave g handles one dst node per iteration, lane j = feature j.
#define NPB 64   // nodes per block
template <int OUT_DIM, bool RELU, bool FEAT_BF16, bool OUT_BF16>
__global__ __launch_bounds__(256) void fused_layer(
        const void* __restrict__ feat,       // [N,64] f32 or bf16 (both self & neighbor)
        const int* __restrict__ off,         // [N+1]
        const int* __restrict__ csr,         // [E] src ids grouped by dst
        const float* __restrict__ Wl,        // [OUT_DIM,64] f32
        const float* __restrict__ Wr,        // [OUT_DIM,64]
        const float* __restrict__ bias,      // [OUT_DIM]
        void* __restrict__ out, int n_nodes) {
    __shared__ float sWl[OUT_DIM][65];   // (65j+k)%32 = (j+k)%32 -> 2-way alias only (free)
    __shared__ float sWr[OUT_DIM][65];
    __shared__ float sB[64];
    __shared__ float sA[4][64];
    __shared__ float sX[4][64];

    for (int idx = threadIdx.x; idx < OUT_DIM * 64; idx += 256) {
        sWl[idx >> 6][idx & 63] = Wl[idx];
        sWr[idx >> 6][idx & 63] = Wr[idx];
    }
    if (threadIdx.x < OUT_DIM) sB[threadIdx.x] = bias[threadIdx.x];

    const int g = threadIdx.x >> 6;   // wave id = node slot
    const int j = threadIdx.x & 63;   // lane = feature
    const int base = blockIdx.x * NPB;

#pragma unroll 1
    for (int it = 0; it < NPB / 4; ++it) {
        const int node = base + it * 4 + g;
        __syncthreads();              // sA/sX reuse + (first iter) weights ready
        if (node < n_nodes) {
            const int e0 = off[node], e1 = off[node + 1];
            float acc0 = 0.f, acc1 = 0.f;
            int i = e0;
            while (i < e1) {
                const int cnt = ((e1 - i) < 64) ? (e1 - i) : 64;
                const int eid = (j < cnt) ? csr[i + j] : 0;
                int t = 0;
                for (; t + 1 < cnt; t += 2) {      // 2-way ILP on the gather
                    const int s0 = __shfl(eid, t);
                    const int s1 = __shfl(eid, t + 1);
                    if (FEAT_BF16) {
                        acc0 += bf2f(((const unsigned short*)feat)[(size_t)s0 * 64 + j]);
                        acc1 += bf2f(((const unsigned short*)feat)[(size_t)s1 * 64 + j]);
                    } else {
                        acc0 += ((const float*)feat)[(size_t)s0 * 64 + j];
                        acc1 += ((const float*)feat)[(size_t)s1 * 64 + j];
                    }
                }
                if (t < cnt) {
                    const int s0 = __shfl(eid, t);
                    acc0 += FEAT_BF16 ? bf2f(((const unsigned short*)feat)[(size_t)s0 * 64 + j])
                                      : ((const float*)feat)[(size_t)s0 * 64 + j];
                }
                i += cnt;
            }
            const int deg = e1 - e0;
            const float inv = (deg > 0) ? 1.0f / (float)deg : 0.0f;
            sA[g][j] = (acc0 + acc1) * inv;
            sX[g][j] = FEAT_BF16 ? bf2f(((const unsigned short*)feat)[(size_t)node * 64 + j])
                                 : ((const float*)feat)[(size_t)node * 64 + j];
        }
        __syncthreads();
        if (node < n_nodes && j < OUT_DIM) {
            float acc = sB[j];
#pragma unroll
            for (int k = 0; k < 64; ++k) {
                acc = fmaf(sA[g][k], sWl[j][k], acc);   // sA[g][k]: wave-broadcast
                acc = fmaf(sX[g][k], sWr[j][k], acc);
            }
            if (RELU) acc = fmaxf(acc, 0.0f);
            if (OUT_BF16)
                ((unsigned short*)out)[(size_t)node * OUT_DIM + j] = f2bf(acc);
            else
                ((float*)out)[(size_t)node * OUT_DIM + j] = acc;
        }
    }
}

extern "C" void kernel_launch(void* const* d_in, const int* in_sizes, int n_in,
                              void* d_out, int out_size, void* d_ws, size_t ws_size,
                              hipStream_t stream) {
    const float* x   = (const float*)d_in[0];   // [N,64] f32
    const int*   ei  = (const int*)d_in[1];     // [2,E] int32 (int64 auto-detected)
    const float* W1l = (const float*)d_in[2];
    const float* W1r = (const float*)d_in[3];
    const float* b1  = (const float*)d_in[4];
    const float* W2l = (const float*)d_in[5];
    const float* W2r = (const float*)d_in[6];
    const float* b2  = (const float*)d_in[7];
    float* out = (float*)d_out;                 // [N,40] f32

    const int n_nodes = in_sizes[0] / 64;
    const int n_edges = in_sizes[1] / 2;

    // ---- workspace layout ----
    const size_t off_bytes = (size_t)(n_nodes + 1) * sizeof(int);
    const size_t cur_bytes = (size_t)n_nodes * sizeof(int);
    const size_t csr_bytes = (size_t)n_edges * sizeof(int);
    const size_t h_f32_bytes  = (size_t)n_nodes * 64 * sizeof(float);
    const size_t h_bf16_bytes = (size_t)n_nodes * 64 * sizeof(unsigned short);
    const size_t fixed = off_bytes + cur_bytes + csr_bytes + 256;
    const bool h_is_f32 = ws_size >= fixed + h_f32_bytes;

    char* ws = (char*)d_ws;
    int* off    = (int*)ws;  ws += off_bytes;
    int* cursor = (int*)ws;  ws += cur_bytes;
    int* csr    = (int*)ws;  ws += csr_bytes;
    int* flag   = (int*)ws;  ws += 256 - (off_bytes + cur_bytes + csr_bytes) % 256
                                   + ((off_bytes + cur_bytes + csr_bytes) % 256 ? 0 : 0);
    // simpler: realign
    ws = (char*)d_ws + ((fixed + 255) / 256) * 256;
    void* h = (void*)ws;

    detect_idx64_kernel<<<1, 64, 0, stream>>>(ei, flag);

    // ---- CSR build (cursor doubles as deg histogram) ----
    hipMemsetAsync(cursor, 0, cur_bytes, stream);
    const int eblocks = (n_edges + 255) / 256;
    hist_kernel<<<eblocks, 256, 0, stream>>>(ei, n_edges, cursor, flag);
    scan_kernel<<<1, SCAN_THREADS, 0, stream>>>(cursor, off, n_nodes);
    hipMemcpyAsync(cursor, off, cur_bytes, hipMemcpyDeviceToDevice, stream);
    fill_kernel<<<eblocks, 256, 0, stream>>>(ei, n_edges, cursor, csr, flag);

    // ---- fused layers ----
    const int lblocks = (n_nodes + NPB - 1) / NPB;
    if (h_is_f32) {
        fused_layer<64, true, false, false><<<lblocks, 256, 0, stream>>>(
            x, off, csr, W1l, W1r, b1, h, n_nodes);
        fused_layer<40, false, false, false><<<lblocks, 256, 0, stream>>>(
            h, off, csr, W2l, W2r, b2, out, n_nodes);
    } else {
        fused_layer<64, true, false, true><<<lblocks, 256, 0, stream>>>(
            x, off, csr, W1l, W1r, b1, h, n_nodes);
        fused_layer<40, false, true, false><<<lblocks, 256, 0, stream>>>(
            h, off, csr, W2l, W2r, b2, out, n_nodes);
    }
    (void)ws_size; (void)h_bf16_bytes;
}

// Round 4
// 593.373 us; speedup vs baseline: 3.8506x; 1.0878x over previous
//
#include <hip/hip_runtime.h>
#include <hip/hip_bf16.h>

// ---------- bf16 helpers (used only in low-workspace fallback tiers) ----------
__device__ __forceinline__ float bf2f(unsigned short u) {
    return __uint_as_float(((unsigned int)u) << 16);
}
__device__ __forceinline__ unsigned short f2bf(float f) {
    unsigned int u = __float_as_uint(f);
    return (unsigned short)((u + 0x7FFFu + ((u >> 16) & 1u)) >> 16);
}

// ---------- detect whether edge_index is int64 (odd 32-bit words all zero) ----------
__global__ void detect_idx64_kernel(const int* __restrict__ e, int* __restrict__ flag) {
    if (threadIdx.x == 0 && blockIdx.x == 0) {
        int z = 0;
#pragma unroll
        for (int i = 0; i < 16; ++i) z |= e[2 * i + 1];
        *flag = (z == 0) ? 1 : 0;
    }
}

// ---------- CSR build: histogram of dst (into cursor) ----------
__global__ void hist_kernel(const int* __restrict__ eidx, int n_edges,
                            int* __restrict__ deg, const int* __restrict__ flag) {
    int e = blockIdx.x * blockDim.x + threadIdx.x;
    if (e >= n_edges) return;
    const bool i64 = (*flag != 0);
    int d = i64 ? eidx[2 * (n_edges + e)] : eidx[n_edges + e];
    atomicAdd(&deg[d], 1);
}

// ---------- CSR build: single-block exclusive scan; writes off AND cursor ----------
#define SCAN_THREADS 1024
__global__ void scan_kernel(int* __restrict__ deg_cursor, int* __restrict__ off, int n) {
    __shared__ int sums[SCAN_THREADS];
    const int t = threadIdx.x;
    const int chunk = (n + SCAN_THREADS - 1) / SCAN_THREADS;
    const int lo = t * chunk;
    const int hi = (lo + chunk < n) ? lo + chunk : n;
    int s = 0;
    for (int i = lo; i < hi; ++i) s += deg_cursor[i];
    sums[t] = s;
    __syncthreads();
    for (int d = 1; d < SCAN_THREADS; d <<= 1) {
        int v = (t >= d) ? sums[t - d] : 0;
        __syncthreads();
        sums[t] += v;
        __syncthreads();
    }
    int run = (t == 0) ? 0 : sums[t - 1];
    for (int i = lo; i < hi; ++i) {
        int d = deg_cursor[i];
        off[i] = run;
        deg_cursor[i] = run;   // cursor initialized for fill (no memcpy needed)
        run += d;
    }
    if (t == SCAN_THREADS - 1 && hi == n) off[n] = run;
}

// ---------- CSR build: fill edge lists ----------
__global__ void fill_kernel(const int* __restrict__ eidx, int n_edges,
                            int* __restrict__ cursor, int* __restrict__ csr,
                            const int* __restrict__ flag) {
    int e = blockIdx.x * blockDim.x + threadIdx.x;
    if (e >= n_edges) return;
    const bool i64 = (*flag != 0);
    int s, d;
    if (i64) { s = eidx[2 * e]; d = eidx[2 * (n_edges + e)]; }
    else     { s = eidx[e];     d = eidx[n_edges + e]; }
    int pos = atomicAdd(&cursor[d], 1);
    csr[pos] = s;
}

// ---------- fused layer: out = [relu]( mean_gather(feat) Wl^T + feat Wr^T + b ) ----------
// 512 threads = 8 waves; wave g owns one node per iteration; lane j = feature.
// sA/sX slots are wave-private -> no barriers inside the node loop.
#define NPB 32   // nodes per block
template <int OUT_DIM, bool RELU, bool FEAT_BF16, bool OUT_BF16>
__global__ __launch_bounds__(512, 8) void fused_layer(
        const void* __restrict__ feat,
        const int* __restrict__ off,
        const int* __restrict__ csr,
        const float* __restrict__ Wl,
        const float* __restrict__ Wr,
        const float* __restrict__ bias,
        void* __restrict__ out, int n_nodes) {
    __shared__ float sWl[OUT_DIM][65];   // bank (j+k)%32 -> 2-way alias (free)
    __shared__ float sWr[OUT_DIM][65];
    __shared__ float sB[OUT_DIM];
    __shared__ float sA[8][64];
    __shared__ float sX[8][64];

    for (int idx = threadIdx.x; idx < OUT_DIM * 64; idx += 512) {
        sWl[idx >> 6][idx & 63] = Wl[idx];
        sWr[idx >> 6][idx & 63] = Wr[idx];
    }
    if (threadIdx.x < OUT_DIM) sB[threadIdx.x] = bias[threadIdx.x];
    __syncthreads();   // weights/bias visible to all waves; only barrier needed

    const int g = threadIdx.x >> 6;
    const int j = threadIdx.x & 63;
    const int base = blockIdx.x * NPB;

#pragma unroll 1
    for (int it = 0; it < NPB / 8; ++it) {
        const int node = base + it * 8 + g;
        if (node >= n_nodes) break;          // node is wave-uniform

        const int e0 = off[node], e1 = off[node + 1];
        float a0 = 0.f, a1 = 0.f, a2 = 0.f, a3 = 0.f;
        int i = e0;
        while (i < e1) {
            const int cnt = ((e1 - i) < 64) ? (e1 - i) : 64;
            const int eid = (j < cnt) ? csr[i + j] : 0;
            int t = 0;
            for (; t + 3 < cnt; t += 4) {    // 4 outstanding gathers
                const int s0 = __shfl(eid, t);
                const int s1 = __shfl(eid, t + 1);
                const int s2 = __shfl(eid, t + 2);
                const int s3 = __shfl(eid, t + 3);
                if (FEAT_BF16) {
                    a0 += bf2f(((const unsigned short*)feat)[(size_t)s0 * 64 + j]);
                    a1 += bf2f(((const unsigned short*)feat)[(size_t)s1 * 64 + j]);
                    a2 += bf2f(((const unsigned short*)feat)[(size_t)s2 * 64 + j]);
                    a3 += bf2f(((const unsigned short*)feat)[(size_t)s3 * 64 + j]);
                } else {
                    a0 += ((const float*)feat)[(size_t)s0 * 64 + j];
                    a1 += ((const float*)feat)[(size_t)s1 * 64 + j];
                    a2 += ((const float*)feat)[(size_t)s2 * 64 + j];
                    a3 += ((const float*)feat)[(size_t)s3 * 64 + j];
                }
            }
            for (; t < cnt; ++t) {
                const int s0 = __shfl(eid, t);
                a0 += FEAT_BF16 ? bf2f(((const unsigned short*)feat)[(size_t)s0 * 64 + j])
                                : ((const float*)feat)[(size_t)s0 * 64 + j];
            }
            i += cnt;
        }
        const int deg = e1 - e0;
        const float inv = (deg > 0) ? 1.0f / (float)deg : 0.0f;
        sA[g][j] = ((a0 + a1) + (a2 + a3)) * inv;
        sX[g][j] = FEAT_BF16 ? bf2f(((const unsigned short*)feat)[(size_t)node * 64 + j])
                             : ((const float*)feat)[(size_t)node * 64 + j];
        // wave-private LDS slot; in-order LDS per wave -> no barrier
        if (j < OUT_DIM) {
            float acc = sB[j];
#pragma unroll
            for (int k = 0; k < 64; ++k) {
                acc = fmaf(sA[g][k], sWl[j][k], acc);   // broadcast read
                acc = fmaf(sX[g][k], sWr[j][k], acc);
            }
            if (RELU) acc = fmaxf(acc, 0.0f);
            if (OUT_BF16)
                ((unsigned short*)out)[(size_t)node * OUT_DIM + j] = f2bf(acc);
            else
                ((float*)out)[(size_t)node * OUT_DIM + j] = acc;
        }
    }
}

// ---------- layer-2 pre-multiply: g2 = h W2l^T, s2 = h W2r^T + b2 (both [N,40]) ----------
__global__ __launch_bounds__(512, 8) void dual_gemm40(
        const float* __restrict__ h,
        const float* __restrict__ Wl, const float* __restrict__ Wr,
        const float* __restrict__ bias,
        float* __restrict__ g2, float* __restrict__ s2, int n_nodes) {
    __shared__ float sWl[40][65];
    __shared__ float sWr[40][65];
    __shared__ float sB[40];
    __shared__ float sX[8][64];

    for (int idx = threadIdx.x; idx < 40 * 64; idx += 512) {
        sWl[idx >> 6][idx & 63] = Wl[idx];
        sWr[idx >> 6][idx & 63] = Wr[idx];
    }
    if (threadIdx.x < 40) sB[threadIdx.x] = bias[threadIdx.x];
    __syncthreads();

    const int g = threadIdx.x >> 6;
    const int j = threadIdx.x & 63;
    const int base = blockIdx.x * NPB;

#pragma unroll 1
    for (int it = 0; it < NPB / 8; ++it) {
        const int node = base + it * 8 + g;
        if (node >= n_nodes) break;
        sX[g][j] = h[(size_t)node * 64 + j];
        if (j < 40) {
            float al = 0.f, ar = sB[j];
#pragma unroll
            for (int k = 0; k < 64; ++k) {
                al = fmaf(sX[g][k], sWl[j][k], al);
                ar = fmaf(sX[g][k], sWr[j][k], ar);
            }
            g2[(size_t)node * 40 + j] = al;
            s2[(size_t)node * 40 + j] = ar;
        }
    }
}

// ---------- layer-2 gather: out = mean_gather(g2) + s2 ----------
__global__ __launch_bounds__(512, 8) void gather_add40(
        const float* __restrict__ g2, const float* __restrict__ s2,
        const int* __restrict__ off, const int* __restrict__ csr,
        float* __restrict__ out, int n_nodes) {
    const int g = threadIdx.x >> 6;
    const int j = threadIdx.x & 63;
    const int jj = (j < 40) ? j : 39;   // clamp: lanes 40-63 dup lane 39 (same line)
    const int base = blockIdx.x * NPB;

#pragma unroll 1
    for (int it = 0; it < NPB / 8; ++it) {
        const int node = base + it * 8 + g;
        if (node >= n_nodes) break;
        const int e0 = off[node], e1 = off[node + 1];
        float a0 = 0.f, a1 = 0.f, a2 = 0.f, a3 = 0.f;
        int i = e0;
        while (i < e1) {
            const int cnt = ((e1 - i) < 64) ? (e1 - i) : 64;
            const int eid = (j < cnt) ? csr[i + j] : 0;
            int t = 0;
            for (; t + 3 < cnt; t += 4) {
                const int s0 = __shfl(eid, t);
                const int s1 = __shfl(eid, t + 1);
                const int s2i = __shfl(eid, t + 2);
                const int s3 = __shfl(eid, t + 3);
                a0 += g2[(size_t)s0 * 40 + jj];
                a1 += g2[(size_t)s1 * 40 + jj];
                a2 += g2[(size_t)s2i * 40 + jj];
                a3 += g2[(size_t)s3 * 40 + jj];
            }
            for (; t < cnt; ++t) {
                const int s0 = __shfl(eid, t);
                a0 += g2[(size_t)s0 * 40 + jj];
            }
            i += cnt;
        }
        if (j < 40) {
            const int deg = e1 - e0;
            const float inv = (deg > 0) ? 1.0f / (float)deg : 0.0f;
            out[(size_t)node * 40 + j] = ((a0 + a1) + (a2 + a3)) * inv
                                         + s2[(size_t)node * 40 + j];
        }
    }
}

extern "C" void kernel_launch(void* const* d_in, const int* in_sizes, int n_in,
                              void* d_out, int out_size, void* d_ws, size_t ws_size,
                              hipStream_t stream) {
    const float* x   = (const float*)d_in[0];
    const int*   ei  = (const int*)d_in[1];
    const float* W1l = (const float*)d_in[2];
    const float* W1r = (const float*)d_in[3];
    const float* b1  = (const float*)d_in[4];
    const float* W2l = (const float*)d_in[5];
    const float* W2r = (const float*)d_in[6];
    const float* b2  = (const float*)d_in[7];
    float* out = (float*)d_out;

    const int n_nodes = in_sizes[0] / 64;
    const int n_edges = in_sizes[1] / 2;

    // ---- workspace layout ----
    const size_t off_b = (size_t)(n_nodes + 1) * sizeof(int);
    const size_t cur_b = (size_t)n_nodes * sizeof(int);
    const size_t csr_b = (size_t)n_edges * sizeof(int);
    const size_t h_b   = (size_t)n_nodes * 64 * sizeof(float);
    const size_t hbf_b = (size_t)n_nodes * 64 * sizeof(unsigned short);
    const size_t gs_b  = (size_t)n_nodes * 40 * sizeof(float);

    char* p = (char*)d_ws;
    int* off    = (int*)p;  p += off_b;
    int* cursor = (int*)p;  p += cur_b;
    int* csr    = (int*)p;  p += csr_b;
    int* flag   = (int*)p;  p += 64;
    size_t used = (size_t)(p - (char*)d_ws);
    used = ((used + 255) / 256) * 256;
    p = (char*)d_ws + used;

    const bool tier1 = ws_size >= used + h_b + 2 * gs_b;   // full path
    const bool tier2 = ws_size >= used + h_b;              // f32 h, fused layer 2

    void*  h  = (void*)p;
    float* g2 = (float*)(p + h_b);
    float* s2 = (float*)(p + h_b + gs_b);

    detect_idx64_kernel<<<1, 64, 0, stream>>>(ei, flag);

    // ---- CSR build ----
    hipMemsetAsync(cursor, 0, cur_b, stream);
    const int eblocks = (n_edges + 255) / 256;
    hist_kernel<<<eblocks, 256, 0, stream>>>(ei, n_edges, cursor, flag);
    scan_kernel<<<1, SCAN_THREADS, 0, stream>>>(cursor, off, n_nodes);
    fill_kernel<<<eblocks, 256, 0, stream>>>(ei, n_edges, cursor, csr, flag);

    const int lblocks = (n_nodes + NPB - 1) / NPB;

    if (tier1) {
        fused_layer<64, true, false, false><<<lblocks, 512, 0, stream>>>(
            x, off, csr, W1l, W1r, b1, h, n_nodes);
        dual_gemm40<<<lblocks, 512, 0, stream>>>(
            (const float*)h, W2l, W2r, b2, g2, s2, n_nodes);
        gather_add40<<<lblocks, 512, 0, stream>>>(
            g2, s2, off, csr, out, n_nodes);
    } else if (tier2) {
        fused_layer<64, true, false, false><<<lblocks, 512, 0, stream>>>(
            x, off, csr, W1l, W1r, b1, h, n_nodes);
        fused_layer<40, false, false, false><<<lblocks, 512, 0, stream>>>(
            h, off, csr, W2l, W2r, b2, out, n_nodes);
    } else {
        fused_layer<64, true, false, true><<<lblocks, 512, 0, stream>>>(
            x, off, csr, W1l, W1r, b1, h, n_nodes);
        fused_layer<40, false, true, false><<<lblocks, 512, 0, stream>>>(
            h, off, csr, W2l, W2r, b2, out, n_nodes);
    }
    (void)hbf_b;
}

// Round 5
// 372.562 us; speedup vs baseline: 6.1327x; 1.5927x over previous
//
#include <hip/hip_runtime.h>
#include <hip/hip_bf16.h>

// ---------- bf16 helpers (used only in low-workspace fallback tiers) ----------
__device__ __forceinline__ float bf2f(unsigned short u) {
    return __uint_as_float(((unsigned int)u) << 16);
}
__device__ __forceinline__ unsigned short f2bf(float f) {
    unsigned int u = __float_as_uint(f);
    return (unsigned short)((u + 0x7FFFu + ((u >> 16) & 1u)) >> 16);
}

// ---------- detect whether edge_index is int64 (odd 32-bit words all zero) ----------
__global__ void detect_idx64_kernel(const int* __restrict__ e, int* __restrict__ flag) {
    if (threadIdx.x == 0 && blockIdx.x == 0) {
        int z = 0;
#pragma unroll
        for (int i = 0; i < 16; ++i) z |= e[2 * i + 1];
        *flag = (z == 0) ? 1 : 0;
    }
}

// ---------- CSR build: histogram of dst (into cursor) ----------
__global__ void hist_kernel(const int* __restrict__ eidx, int n_edges,
                            int* __restrict__ deg, const int* __restrict__ flag) {
    int e = blockIdx.x * blockDim.x + threadIdx.x;
    if (e >= n_edges) return;
    const bool i64 = (*flag != 0);
    int d = i64 ? eidx[2 * (n_edges + e)] : eidx[n_edges + e];
    atomicAdd(&deg[d], 1);
}

// ---------- 3-phase parallel exclusive scan over deg[n] ----------
// TILE = 1024 elements per block (256 threads x 4)
#define TILE 1024
__global__ void scan_p1(const int* __restrict__ deg, int* __restrict__ bsum, int n) {
    __shared__ int red[256];
    const int t = threadIdx.x;
    const int base = blockIdx.x * TILE + t * 4;
    int s = 0;
#pragma unroll
    for (int k = 0; k < 4; ++k) {
        int i = base + k;
        if (i < n) s += deg[i];
    }
    red[t] = s;
    __syncthreads();
    for (int d = 128; d > 0; d >>= 1) {
        if (t < d) red[t] += red[t + d];
        __syncthreads();
    }
    if (t == 0) bsum[blockIdx.x] = red[0];
}

// single block, 1024 threads: exclusive-scan bsum[nb] in place; off[n] = total
__global__ void scan_p2(int* __restrict__ bsum, int* __restrict__ off, int nb, int n) {
    __shared__ int s[1024];
    const int t = threadIdx.x;
    s[t] = (t < nb) ? bsum[t] : 0;
    __syncthreads();
    for (int d = 1; d < 1024; d <<= 1) {
        int v = (t >= d) ? s[t - d] : 0;
        __syncthreads();
        s[t] += v;
        __syncthreads();
    }
    if (t < nb) bsum[t] = (t == 0) ? 0 : s[t - 1];
    if (t == 0) off[n] = s[nb - 1];
}

// per-block: re-scan tile, add block offset, write off[] and cursor[]
// (deg may alias cursor: each thread reads its own 4 elems before writing them)
__global__ void scan_p3(const int* __restrict__ deg, const int* __restrict__ bsum,
                        int* __restrict__ off, int* __restrict__ cursor, int n) {
    __shared__ int red[256];
    const int t = threadIdx.x;
    const int base = blockIdx.x * TILE + t * 4;
    int v0 = 0, v1 = 0, v2 = 0, v3 = 0;
    if (base + 0 < n) v0 = deg[base + 0];
    if (base + 1 < n) v1 = deg[base + 1];
    if (base + 2 < n) v2 = deg[base + 2];
    if (base + 3 < n) v3 = deg[base + 3];
    const int mysum = v0 + v1 + v2 + v3;
    red[t] = mysum;
    __syncthreads();
    for (int d = 1; d < 256; d <<= 1) {
        int u = (t >= d) ? red[t - d] : 0;
        __syncthreads();
        red[t] += u;
        __syncthreads();
    }
    int run = bsum[blockIdx.x] + red[t] - mysum;   // exclusive prefix for this thread
    if (base + 0 < n) { off[base + 0] = run; cursor[base + 0] = run; run += v0; }
    if (base + 1 < n) { off[base + 1] = run; cursor[base + 1] = run; run += v1; }
    if (base + 2 < n) { off[base + 2] = run; cursor[base + 2] = run; run += v2; }
    if (base + 3 < n) { off[base + 3] = run; cursor[base + 3] = run; run += v3; }
}

// ---------- CSR build: fill edge lists ----------
__global__ void fill_kernel(const int* __restrict__ eidx, int n_edges,
                            int* __restrict__ cursor, int* __restrict__ csr,
                            const int* __restrict__ flag) {
    int e = blockIdx.x * blockDim.x + threadIdx.x;
    if (e >= n_edges) return;
    const bool i64 = (*flag != 0);
    int s, d;
    if (i64) { s = eidx[2 * e]; d = eidx[2 * (n_edges + e)]; }
    else     { s = eidx[e];     d = eidx[n_edges + e]; }
    int pos = atomicAdd(&cursor[d], 1);
    csr[pos] = s;
}

// ---------- fused layer: out = [relu]( mean_gather(feat) Wl^T + feat Wr^T + b ) ----------
// 512 threads = 8 waves; wave g owns one node per iteration; lane j = feature.
#define NPB 32   // nodes per block
template <int OUT_DIM, bool RELU, bool FEAT_BF16, bool OUT_BF16>
__global__ __launch_bounds__(512, 8) void fused_layer(
        const void* __restrict__ feat,
        const int* __restrict__ off,
        const int* __restrict__ csr,
        const float* __restrict__ Wl,
        const float* __restrict__ Wr,
        const float* __restrict__ bias,
        void* __restrict__ out, int n_nodes) {
    __shared__ float sWl[OUT_DIM][65];   // bank (j+k)%32 -> 2-way alias (free)
    __shared__ float sWr[OUT_DIM][65];
    __shared__ float sB[OUT_DIM];
    __shared__ float sA[8][64];
    __shared__ float sX[8][64];

    for (int idx = threadIdx.x; idx < OUT_DIM * 64; idx += 512) {
        sWl[idx >> 6][idx & 63] = Wl[idx];
        sWr[idx >> 6][idx & 63] = Wr[idx];
    }
    if (threadIdx.x < OUT_DIM) sB[threadIdx.x] = bias[threadIdx.x];
    __syncthreads();   // weights/bias visible; only barrier needed

    const int g = threadIdx.x >> 6;
    const int j = threadIdx.x & 63;
    const int base = blockIdx.x * NPB;

#pragma unroll 1
    for (int it = 0; it < NPB / 8; ++it) {
        const int node = base + it * 8 + g;
        if (node >= n_nodes) break;          // node is wave-uniform

        const int e0 = off[node], e1 = off[node + 1];
        float a0 = 0.f, a1 = 0.f, a2 = 0.f, a3 = 0.f;
        int i = e0;
        while (i < e1) {
            const int cnt = ((e1 - i) < 64) ? (e1 - i) : 64;
            const int eid = (j < cnt) ? csr[i + j] : 0;
            int t = 0;
            for (; t + 3 < cnt; t += 4) {    // 4 outstanding gathers
                const int s0 = __shfl(eid, t);
                const int s1 = __shfl(eid, t + 1);
                const int s2 = __shfl(eid, t + 2);
                const int s3 = __shfl(eid, t + 3);
                if (FEAT_BF16) {
                    a0 += bf2f(((const unsigned short*)feat)[(size_t)s0 * 64 + j]);
                    a1 += bf2f(((const unsigned short*)feat)[(size_t)s1 * 64 + j]);
                    a2 += bf2f(((const unsigned short*)feat)[(size_t)s2 * 64 + j]);
                    a3 += bf2f(((const unsigned short*)feat)[(size_t)s3 * 64 + j]);
                } else {
                    a0 += ((const float*)feat)[(size_t)s0 * 64 + j];
                    a1 += ((const float*)feat)[(size_t)s1 * 64 + j];
                    a2 += ((const float*)feat)[(size_t)s2 * 64 + j];
                    a3 += ((const float*)feat)[(size_t)s3 * 64 + j];
                }
            }
            for (; t < cnt; ++t) {
                const int s0 = __shfl(eid, t);
                a0 += FEAT_BF16 ? bf2f(((const unsigned short*)feat)[(size_t)s0 * 64 + j])
                                : ((const float*)feat)[(size_t)s0 * 64 + j];
            }
            i += cnt;
        }
        const int deg = e1 - e0;
        const float inv = (deg > 0) ? 1.0f / (float)deg : 0.0f;
        sA[g][j] = ((a0 + a1) + (a2 + a3)) * inv;
        sX[g][j] = FEAT_BF16 ? bf2f(((const unsigned short*)feat)[(size_t)node * 64 + j])
                             : ((const float*)feat)[(size_t)node * 64 + j];
        // wave-private LDS slot; in-order LDS per wave -> no barrier
        if (j < OUT_DIM) {
            float acc = sB[j];
#pragma unroll
            for (int k = 0; k < 64; ++k) {
                acc = fmaf(sA[g][k], sWl[j][k], acc);   // broadcast read
                acc = fmaf(sX[g][k], sWr[j][k], acc);
            }
            if (RELU) acc = fmaxf(acc, 0.0f);
            if (OUT_BF16)
                ((unsigned short*)out)[(size_t)node * OUT_DIM + j] = f2bf(acc);
            else
                ((float*)out)[(size_t)node * OUT_DIM + j] = acc;
        }
    }
}

// ---------- layer-2 pre-multiply: g2 = h W2l^T, s2 = h W2r^T + b2 (both [N,40]) ----------
__global__ __launch_bounds__(512, 8) void dual_gemm40(
        const float* __restrict__ h,
        const float* __restrict__ Wl, const float* __restrict__ Wr,
        const float* __restrict__ bias,
        float* __restrict__ g2, float* __restrict__ s2, int n_nodes) {
    __shared__ float sWl[40][65];
    __shared__ float sWr[40][65];
    __shared__ float sB[40];
    __shared__ float sX[8][64];

    for (int idx = threadIdx.x; idx < 40 * 64; idx += 512) {
        sWl[idx >> 6][idx & 63] = Wl[idx];
        sWr[idx >> 6][idx & 63] = Wr[idx];
    }
    if (threadIdx.x < 40) sB[threadIdx.x] = bias[threadIdx.x];
    __syncthreads();

    const int g = threadIdx.x >> 6;
    const int j = threadIdx.x & 63;
    const int base = blockIdx.x * NPB;

#pragma unroll 1
    for (int it = 0; it < NPB / 8; ++it) {
        const int node = base + it * 8 + g;
        if (node >= n_nodes) break;
        sX[g][j] = h[(size_t)node * 64 + j];
        if (j < 40) {
            float al = 0.f, ar = sB[j];
#pragma unroll
            for (int k = 0; k < 64; ++k) {
                al = fmaf(sX[g][k], sWl[j][k], al);
                ar = fmaf(sX[g][k], sWr[j][k], ar);
            }
            g2[(size_t)node * 40 + j] = al;
            s2[(size_t)node * 40 + j] = ar;
        }
    }
}

// ---------- layer-2 gather: out = mean_gather(g2) + s2 ----------
__global__ __launch_bounds__(512, 8) void gather_add40(
        const float* __restrict__ g2, const float* __restrict__ s2,
        const int* __restrict__ off, const int* __restrict__ csr,
        float* __restrict__ out, int n_nodes) {
    const int g = threadIdx.x >> 6;
    const int j = threadIdx.x & 63;
    const int jj = (j < 40) ? j : 39;   // clamp: lanes 40-63 dup lane 39 (same line)
    const int base = blockIdx.x * NPB;

#pragma unroll 1
    for (int it = 0; it < NPB / 8; ++it) {
        const int node = base + it * 8 + g;
        if (node >= n_nodes) break;
        const int e0 = off[node], e1 = off[node + 1];
        float a0 = 0.f, a1 = 0.f, a2 = 0.f, a3 = 0.f;
        int i = e0;
        while (i < e1) {
            const int cnt = ((e1 - i) < 64) ? (e1 - i) : 64;
            const int eid = (j < cnt) ? csr[i + j] : 0;
            int t = 0;
            for (; t + 3 < cnt; t += 4) {
                const int s0 = __shfl(eid, t);
                const int s1 = __shfl(eid, t + 1);
                const int s2i = __shfl(eid, t + 2);
                const int s3 = __shfl(eid, t + 3);
                a0 += g2[(size_t)s0 * 40 + jj];
                a1 += g2[(size_t)s1 * 40 + jj];
                a2 += g2[(size_t)s2i * 40 + jj];
                a3 += g2[(size_t)s3 * 40 + jj];
            }
            for (; t < cnt; ++t) {
                const int s0 = __shfl(eid, t);
                a0 += g2[(size_t)s0 * 40 + jj];
            }
            i += cnt;
        }
        if (j < 40) {
            const int deg = e1 - e0;
            const float inv = (deg > 0) ? 1.0f / (float)deg : 0.0f;
            out[(size_t)node * 40 + j] = ((a0 + a1) + (a2 + a3)) * inv
                                         + s2[(size_t)node * 40 + j];
        }
    }
}

extern "C" void kernel_launch(void* const* d_in, const int* in_sizes, int n_in,
                              void* d_out, int out_size, void* d_ws, size_t ws_size,
                              hipStream_t stream) {
    const float* x   = (const float*)d_in[0];
    const int*   ei  = (const int*)d_in[1];
    const float* W1l = (const float*)d_in[2];
    const float* W1r = (const float*)d_in[3];
    const float* b1  = (const float*)d_in[4];
    const float* W2l = (const float*)d_in[5];
    const float* W2r = (const float*)d_in[6];
    const float* b2  = (const float*)d_in[7];
    float* out = (float*)d_out;

    const int n_nodes = in_sizes[0] / 64;
    const int n_edges = in_sizes[1] / 2;

    // ---- workspace layout ----
    const size_t off_b  = (size_t)(n_nodes + 1) * sizeof(int);
    const size_t cur_b  = (size_t)n_nodes * sizeof(int);
    const size_t csr_b  = (size_t)n_edges * sizeof(int);
    const size_t h_b    = (size_t)n_nodes * 64 * sizeof(float);
    const size_t gs_b   = (size_t)n_nodes * 40 * sizeof(float);
    const size_t bsum_b = 1024 * sizeof(int);

    char* p = (char*)d_ws;
    int* off    = (int*)p;  p += off_b;
    int* cursor = (int*)p;  p += cur_b;
    int* csr    = (int*)p;  p += csr_b;
    int* flag   = (int*)p;  p += 64;
    int* bsum   = (int*)p;  p += bsum_b;
    size_t used = (size_t)(p - (char*)d_ws);
    used = ((used + 255) / 256) * 256;
    p = (char*)d_ws + used;

    const bool tier1 = ws_size >= used + h_b + 2 * gs_b;   // full path
    const bool tier2 = ws_size >= used + h_b;              // f32 h, fused layer 2

    void*  h  = (void*)p;
    float* g2 = (float*)(p + h_b);
    float* s2 = (float*)(p + h_b + gs_b);

    detect_idx64_kernel<<<1, 64, 0, stream>>>(ei, flag);

    // ---- CSR build ----
    hipMemsetAsync(cursor, 0, cur_b, stream);
    const int eblocks = (n_edges + 255) / 256;
    hist_kernel<<<eblocks, 256, 0, stream>>>(ei, n_edges, cursor, flag);

    const int nb = (n_nodes + TILE - 1) / TILE;            // 98 for N=100k (<=1024)
    scan_p1<<<nb, 256, 0, stream>>>(cursor, bsum, n_nodes);
    scan_p2<<<1, 1024, 0, stream>>>(bsum, off, nb, n_nodes);
    scan_p3<<<nb, 256, 0, stream>>>(cursor, bsum, off, cursor, n_nodes);

    fill_kernel<<<eblocks, 256, 0, stream>>>(ei, n_edges, cursor, csr, flag);

    const int lblocks = (n_nodes + NPB - 1) / NPB;

    if (tier1) {
        fused_layer<64, true, false, false><<<lblocks, 512, 0, stream>>>(
            x, off, csr, W1l, W1r, b1, h, n_nodes);
        dual_gemm40<<<lblocks, 512, 0, stream>>>(
            (const float*)h, W2l, W2r, b2, g2, s2, n_nodes);
        gather_add40<<<lblocks, 512, 0, stream>>>(
            g2, s2, off, csr, out, n_nodes);
    } else if (tier2) {
        fused_layer<64, true, false, false><<<lblocks, 512, 0, stream>>>(
            x, off, csr, W1l, W1r, b1, h, n_nodes);
        fused_layer<40, false, false, false><<<lblocks, 512, 0, stream>>>(
            h, off, csr, W2l, W2r, b2, out, n_nodes);
    } else {
        fused_layer<64, true, false, true><<<lblocks, 512, 0, stream>>>(
            x, off, csr, W1l, W1r, b1, h, n_nodes);
        fused_layer<40, false, true, false><<<lblocks, 512, 0, stream>>>(
            h, off, csr, W2l, W2r, b2, out, n_nodes);
    }
}